// Round 10
// baseline (340.009 us; speedup 1.0000x reference)
//
#include <hip/hip_runtime.h>
#include <hip/hip_bf16.h>
#include <math.h>

#define BB 8
#define NN 2048
#define DD 128
#define LL 3
#define GN_EPS 1e-5f

typedef __attribute__((ext_vector_type(8))) short bf16x8;
typedef __attribute__((ext_vector_type(4))) float f32x4;

// raw v_sqrt_f32 (1 inst)
#define FSQRT(x) __builtin_amdgcn_sqrtf(x)

// round-half-up f32 -> bf16 bits
__device__ __forceinline__ unsigned short f2bf(float f) {
    union { float f; unsigned u; } v; v.f = f;
    return (unsigned short)((v.u + 0x8000u) >> 16);
}

__device__ __forceinline__ float fast_tanh(float x) {
    float e = __expf(-2.0f * fabsf(x));
    float t = (1.0f - e) * __builtin_amdgcn_rcpf(1.0f + e);
    return copysignf(t, x);
}

// GraphNorm affine fold: h_norm = s*h + c
__device__ __forceinline__ void stats_sc(float ps, float pq, float a, float w_,
                                         float b_, float& s, float& c) {
    const float inv_n = 1.0f / (float)NN;
    float mean = ps * inv_n;
    float msq  = pq * inv_n;
    float var  = msq - mean * mean * a * (2.0f - a);
    float rstd = rsqrtf(var + GN_EPS);
    s = w_ * rstd;
    c = b_ - s * (a * mean);
}

// ---------------------------------------------------------------------------
// K0: prep_wg — pack Wg (3x128x128 f32) into bf16 MFMA frag order.
// ---------------------------------------------------------------------------
__global__ __launch_bounds__(256)
void prep_wg(const float* __restrict__ Wg, unsigned short* __restrict__ wgf)
{
    const int f = blockIdx.x * 256 + threadIdx.x;    // < 3*128*128
    const int l  = f >> 14;
    const int r  = f & 16383;
    const int dp = r >> 7;
    const int e  = r & 127;
    const int dpt = dp >> 4, ll = dp & 15;
    const int kc  = e >> 5,  eo = e & 31;
    wgf[((((l * 8 + dpt) * 4 + kc) * 16 + ll) << 5) + eo] = f2bf(Wg[f]);
}

// ---------------------------------------------------------------------------
// K1: deg — dinv[b][n] = rsqrt( sum_m dist(n,m) + 1 ).
// ---------------------------------------------------------------------------
__global__ __launch_bounds__(256)
void deg_kernel(const float* __restrict__ inst, float* __restrict__ dinv)
{
    __shared__ float cs[NN * 2];
    const int b   = blockIdx.x >> 6;
    const int n0  = (blockIdx.x & 63) * 32;
    const int tid = threadIdx.x;
    const int w    = tid >> 6;
    const int lane = tid & 63;

    const float* instb = inst + b * NN * 2;
    for (int i = tid; i < (NN * 2) / 4; i += 256)
        ((float4*)cs)[i] = ((const float4*)instb)[i];
    __syncthreads();

    float mx[4][8], my[4][8];
    #pragma unroll
    for (int c = 0; c < 4; ++c)
        #pragma unroll
        for (int e = 0; e < 8; ++e) {
            int m = c * 512 + lane * 8 + e;
            mx[c][e] = cs[m * 2 + 0];
            my[c][e] = cs[m * 2 + 1];
        }

    for (int r = 0; r < 8; ++r) {
        const int n = n0 + w * 8 + r;
        const float nxv = cs[n * 2 + 0];
        const float nyv = cs[n * 2 + 1];
        float rs = 0.f;
        #pragma unroll
        for (int c = 0; c < 4; ++c)
            #pragma unroll
            for (int e = 0; e < 8; ++e) {
                float dx = nxv - mx[c][e];
                float dy = nyv - my[c][e];
                rs += FSQRT(dx * dx + dy * dy);   // diag contributes 0
            }
        #pragma unroll
        for (int off = 1; off < 64; off <<= 1) rs += __shfl_xor(rs, off);
        if (lane == 0) dinv[b * NN + n] = rsqrtf(rs + 1.0f);
    }
}

// ---------------------------------------------------------------------------
// K2: proj_node + zero all per-layer stats buffers
// ---------------------------------------------------------------------------
__global__ __launch_bounds__(256)
void proj_kernel(const float* __restrict__ inst, const float* __restrict__ Wn,
                 const float* __restrict__ bn, float* __restrict__ h,
                 float* __restrict__ psum, float* __restrict__ psq)
{
    const int idx = blockIdx.x * 256 + threadIdx.x;
    const int d   = idx & (DD - 1);
    const int row = idx >> 7;
    const float x0 = inst[row * 2 + 0];
    const float x1 = inst[row * 2 + 1];
    h[idx] = x0 * Wn[d * 2 + 0] + x1 * Wn[d * 2 + 1] + bn[d];
    if (blockIdx.x == 0) {
        for (int i = threadIdx.x; i < LL * BB * DD; i += 256) {
            psum[i] = 0.0f; psq[i] = 0.0f;
        }
    }
}

// ---------------------------------------------------------------------------
// K3: lin (MFMA). tT[b][d'][m] = bf16( dinv[m] * sum_e norm(h)[m][e]*Wg[d'][e] )
// blockIdx = [tile(6b)<<3 | b(3b)] so batch b's tT is WRITTEN on XCD b —
// agg (same swizzle) then reads it from the local L2 (no cross-XCD dirty lines).
// ---------------------------------------------------------------------------
template <bool HP>
__global__ __launch_bounds__(256)
void lin_mfma(const float* __restrict__ h, const unsigned short* __restrict__ wgf_l,
              const float* __restrict__ dinv,
              const float* __restrict__ psumP, const float* __restrict__ psqP,
              const float* __restrict__ ga, const float* __restrict__ gw,
              const float* __restrict__ gb, unsigned short* __restrict__ tT)
{
    __shared__ float sL[DD], cL[DD];
    const int tid  = threadIdx.x;
    const int b    = blockIdx.x & 7;
    const int row0 = b * NN + (blockIdx.x >> 3) * 32;
    const int w    = tid >> 6;
    const int lane = tid & 63;
    const int lq   = lane >> 4;
    const int ll   = lane & 15;

    if (tid < DD) {
        float s = 1.0f, c = 0.0f;
        if (HP)
            stats_sc(psumP[b * DD + tid], psqP[b * DD + tid],
                     ga[tid], gw[tid], gb[tid], s, c);
        sL[tid] = s; cL[tid] = c;
    }
    __syncthreads();

    bf16x8 aw[2][4];
    #pragma unroll
    for (int mt = 0; mt < 2; ++mt) {
        const int dpt = 2 * w + mt;
        #pragma unroll
        for (int kc = 0; kc < 4; ++kc)
            aw[mt][kc] = *(const bf16x8*)&wgf_l[(((dpt * 4 + kc) * 16 + ll) << 5) + lq * 8];
    }

    bf16x8 bh[2][4];
    #pragma unroll
    for (int nt = 0; nt < 2; ++nt) {
        const float* hrow = h + (size_t)(row0 + nt * 16 + ll) * DD;
        #pragma unroll
        for (int kc = 0; kc < 4; ++kc) {
            float4 h0 = *(const float4*)&hrow[kc * 32 + lq * 8];
            float4 h1 = *(const float4*)&hrow[kc * 32 + lq * 8 + 4];
            const int e0 = kc * 32 + lq * 8;
            bf16x8 p;
            p[0] = (short)f2bf(fmaf(sL[e0 + 0], h0.x, cL[e0 + 0]));
            p[1] = (short)f2bf(fmaf(sL[e0 + 1], h0.y, cL[e0 + 1]));
            p[2] = (short)f2bf(fmaf(sL[e0 + 2], h0.z, cL[e0 + 2]));
            p[3] = (short)f2bf(fmaf(sL[e0 + 3], h0.w, cL[e0 + 3]));
            p[4] = (short)f2bf(fmaf(sL[e0 + 4], h1.x, cL[e0 + 4]));
            p[5] = (short)f2bf(fmaf(sL[e0 + 5], h1.y, cL[e0 + 5]));
            p[6] = (short)f2bf(fmaf(sL[e0 + 6], h1.z, cL[e0 + 6]));
            p[7] = (short)f2bf(fmaf(sL[e0 + 7], h1.w, cL[e0 + 7]));
            bh[nt][kc] = p;
        }
    }

    f32x4 acc[2][2];   // [nt][mt]
    #pragma unroll
    for (int i = 0; i < 2; ++i)
        #pragma unroll
        for (int j = 0; j < 2; ++j) acc[i][j] = (f32x4)0.0f;

    #pragma unroll
    for (int kc = 0; kc < 4; ++kc)
        #pragma unroll
        for (int nt = 0; nt < 2; ++nt)
            #pragma unroll
            for (int mt = 0; mt < 2; ++mt)
                acc[nt][mt] = __builtin_amdgcn_mfma_f32_16x16x32_bf16(
                    bh[nt][kc], aw[mt][kc], acc[nt][mt], 0, 0, 0);

    // store: lane holds d' = (2w+mt)*16+ll, nodes = nbase+nt*16+lq*4+reg
    const int nbase = row0 & (NN - 1);
    #pragma unroll
    for (int nt = 0; nt < 2; ++nt) {
        const int node0 = nbase + nt * 16 + lq * 4;
        float4 di4 = *(const float4*)&dinv[row0 + nt * 16 + lq * 4];
        #pragma unroll
        for (int mt = 0; mt < 2; ++mt) {
            const int dp = (2 * w + mt) * 16 + ll;
            ushort4 pk;
            pk.x = f2bf(acc[nt][mt][0] * di4.x);
            pk.y = f2bf(acc[nt][mt][1] * di4.y);
            pk.z = f2bf(acc[nt][mt][2] * di4.z);
            pk.w = f2bf(acc[nt][mt][3] * di4.w);
            *(ushort4*)&tT[(size_t)(b * DD + dp) * NN + node0] = pk;
        }
    }
}

// ---------------------------------------------------------------------------
// K4: agg — max-occupancy version.  Block 16n x 128d, grid 1024 (128 tiles x
// 8 batches, blockIdx&7 = batch -> XCD).  4 waves = 4-way K-split (wave w:
// m in [w*512,(w+1)*512), 16 chunks of 32).  No coord LDS (m/n coords from
// global, L1-resident), no GLL, no sched intrinsics — latency hidden by
// ~12 waves/CU.  Reduction: 16 KB LDS, 2 rounds.  Fused epilogue.
// ---------------------------------------------------------------------------
template <bool HP>
__global__ __launch_bounds__(256, 3)
void agg_mfma(const float* __restrict__ inst, const unsigned short* __restrict__ tT,
              const float* __restrict__ dinv, const float* __restrict__ bg_l,
              const float* __restrict__ psumP, const float* __restrict__ psqP,
              const float* __restrict__ ga, const float* __restrict__ gw,
              const float* __restrict__ gb,
              float* __restrict__ h, float* __restrict__ psum, float* __restrict__ psq)
{
    __shared__ f32x4 red[4][4][64];       // 16 KB reduction buffer
    const int b    = blockIdx.x & 7;
    const int n0   = (blockIdx.x >> 3) * 16;
    const int tid  = threadIdx.x;
    const int w    = tid >> 6;
    const int lane = tid & 63;
    const int lq   = lane >> 4;
    const int ll   = lane & 15;

    const float* instb = inst + b * NN * 2;
    const int n = n0 + ll;                 // this lane's output row
    const float nxv = instb[n * 2 + 0];
    const float nyv = instb[n * 2 + 1];

    // tT pointers (A-operand): row d = dt*16+ll, this wave's K-range
    const unsigned short* tTb = tT + (size_t)b * DD * NN + w * 512 + lq * 8;
    const unsigned short* gbp[8];
    #pragma unroll
    for (int dt = 0; dt < 8; ++dt)
        gbp[dt] = tTb + (size_t)(dt * 16 + ll) * NN;

    f32x4 acc[8];
    #pragma unroll
    for (int j = 0; j < 8; ++j) acc[j] = (f32x4)0.0f;

    const int mwbase = w * 512;
    const int diagmb = n0 & ~31;           // chunk base containing the diagonal

    for (int kc = 0; kc < 16; ++kc) {
        const int mo = kc * 32;
        const int mb = mwbase + mo;

        // A-frags (tT) for this chunk
        bf16x8 fb[8];
        #pragma unroll
        for (int dt = 0; dt < 8; ++dt)
            fb[dt] = *(const bf16x8*)(gbp[dt] + mo);

        // m-coords from global (L1-hot, quad-broadcast): m = mb + lq*8 + j
        const float* cp = instb + (mb + lq * 8) * 2;
        float4 c01 = *(const float4*)(cp + 0);
        float4 c23 = *(const float4*)(cp + 4);
        float4 c45 = *(const float4*)(cp + 8);
        float4 c67 = *(const float4*)(cp + 12);
        float mxx[8] = { c01.x, c01.z, c23.x, c23.z, c45.x, c45.z, c67.x, c67.z };
        float myy[8] = { c01.y, c01.w, c23.y, c23.w, c45.y, c45.w, c67.y, c67.w };

        // B-frag: dist(n, m); self-loop = 1.0 on the diagonal
        float dist[8];
        #pragma unroll
        for (int j = 0; j < 8; ++j) {
            float dx = nxv - mxx[j];
            float dy = nyv - myy[j];
            dist[j] = FSQRT(dx * dx + dy * dy);
        }
        if (mb == diagmb) {
            const int base = mb + lq * 8;
            #pragma unroll
            for (int j = 0; j < 8; ++j)
                if (base + j == n) dist[j] = 1.0f;
        }
        union { bf16x8 v; __hip_bfloat162 h2[4]; } u;
        #pragma unroll
        for (int p = 0; p < 4; ++p)
            u.h2[p] = __float22bfloat162_rn(make_float2(dist[2 * p], dist[2 * p + 1]));
        bf16x8 bfr = u.v;

        #pragma unroll
        for (int dt = 0; dt < 8; ++dt)
            acc[dt] = __builtin_amdgcn_mfma_f32_16x16x32_bf16(fb[dt], bfr, acc[dt], 0, 0, 0);
    }

    // ---- cross-wave reduction + fused epilogue (2 rounds of 4 frags)
    const float di = dinv[b * NN + n];
    #pragma unroll
    for (int round = 0; round < 2; ++round) {
        #pragma unroll
        for (int fd = 0; fd < 4; ++fd)
            red[w][fd][lane] = acc[round * 4 + fd];
        __syncthreads();

        const int dt = round * 4 + w;      // this wave's output frag
        f32x4 v = red[0][w][lane];
        v += red[1][w][lane];
        v += red[2][w][lane];
        v += red[3][w][lane];

        const int d0 = dt * 16 + lq * 4;
        float4 bg4 = *(const float4*)&bg_l[d0];
        float sres[4] = {1.f, 1.f, 1.f, 1.f}, cres[4] = {0.f, 0.f, 0.f, 0.f};
        if (HP) {
            float4 ps4 = *(const float4*)&psumP[b * DD + d0];
            float4 pq4 = *(const float4*)&psqP[b * DD + d0];
            float4 ga4 = *(const float4*)&ga[d0];
            float4 gw4 = *(const float4*)&gw[d0];
            float4 gb4 = *(const float4*)&gb[d0];
            stats_sc(ps4.x, pq4.x, ga4.x, gw4.x, gb4.x, sres[0], cres[0]);
            stats_sc(ps4.y, pq4.y, ga4.y, gw4.y, gb4.y, sres[1], cres[1]);
            stats_sc(ps4.z, pq4.z, ga4.z, gw4.z, gb4.z, sres[2], cres[2]);
            stats_sc(ps4.w, pq4.w, ga4.w, gw4.w, gb4.w, sres[3], cres[3]);
        }
        size_t idx = ((size_t)b * NN + n) * DD + d0;
        float4 hv = *(const float4*)&h[idx];
        float outv[4];
        #pragma unroll
        for (int r = 0; r < 4; ++r) {
            float pre = di * v[r] + (&bg4.x)[r];
            outv[r] = fast_tanh(pre) + fmaf(sres[r], (&hv.x)[r], cres[r]);
        }
        float4 ov = { outv[0], outv[1], outv[2], outv[3] };
        *(float4*)&h[idx] = ov;

        // stats: sum over the 16 n's (ll dimension)
        float hs[4], hq[4];
        #pragma unroll
        for (int r = 0; r < 4; ++r) { hs[r] = outv[r]; hq[r] = outv[r] * outv[r]; }
        #pragma unroll
        for (int off = 1; off < 16; off <<= 1) {
            #pragma unroll
            for (int r = 0; r < 4; ++r) {
                hs[r] += __shfl_xor(hs[r], off);
                hq[r] += __shfl_xor(hq[r], off);
            }
        }
        if (ll == 0) {
            #pragma unroll
            for (int r = 0; r < 4; ++r) {
                atomicAdd(&psum[b * DD + d0 + r], hs[r]);
                atomicAdd(&psq[b * DD + d0 + r], hq[r]);
            }
        }
        __syncthreads();
    }
}

// ---------------------------------------------------------------------------
// K5: final apply with in-thread stats from layer-2 buffers
// ---------------------------------------------------------------------------
__global__ __launch_bounds__(256)
void apply_kernel(const float* __restrict__ h,
                  const float* __restrict__ psum2, const float* __restrict__ psq2,
                  const float* __restrict__ ga, const float* __restrict__ gw,
                  const float* __restrict__ gb, float* __restrict__ dst)
{
    const int i4 = blockIdx.x * 256 + threadIdx.x;    // < B*N*D/4
    const int dg = (i4 & 31) * 4;
    const int b  = i4 >> 16;                          // N*D/4 = 65536
    float4 hv = ((const float4*)h)[i4];
    float o[4];
    #pragma unroll
    for (int j = 0; j < 4; ++j) {
        const int d = dg + j;
        float s, c;
        stats_sc(psum2[b * DD + d], psq2[b * DD + d], ga[d], gw[d], gb[d], s, c);
        o[j] = fmaf(s, (&hv.x)[j], c);
    }
    float4 ov = { o[0], o[1], o[2], o[3] };
    ((float4*)dst)[i4] = ov;
}

// ---------------------------------------------------------------------------
extern "C" void kernel_launch(void* const* d_in, const int* in_sizes, int n_in,
                              void* d_out, int out_size, void* d_ws, size_t ws_size,
                              hipStream_t stream)
{
    const float* inst = (const float*)d_in[0];
    const float* Wn   = (const float*)d_in[1];
    const float* bn   = (const float*)d_in[2];
    const float* Wg   = (const float*)d_in[3];
    const float* bg   = (const float*)d_in[4];
    const float* gw   = (const float*)d_in[5];
    const float* gb   = (const float*)d_in[6];
    const float* ga   = (const float*)d_in[7];
    float* out = (float*)d_out;

    float* ws   = (float*)d_ws;
    float* dinv = ws;                                   // B*N
    float* h    = dinv + BB * NN;                       // B*N*D
    float* psum = h + (size_t)BB * NN * DD;             // LL*B*D
    float* psq  = psum + LL * BB * DD;                  // LL*B*D
    unsigned short* wgf = (unsigned short*)(psq + LL * BB * DD);  // LL*D*D bf16
    unsigned short* tT  = wgf + LL * DD * DD;                     // B*D*N bf16 (8MB)

    prep_wg<<<(LL * DD * DD) / 256, 256, 0, stream>>>(Wg, wgf);
    deg_kernel<<<BB * 64, 256, 0, stream>>>(inst, dinv);
    proj_kernel<<<(BB * NN * DD) / 256, 256, 0, stream>>>(inst, Wn, bn, h, psum, psq);

    for (int l = 0; l < LL; ++l) {
        const unsigned short* wgl = wgf + (size_t)l * DD * DD;
        const float* psP = psum + (size_t)(l - 1) * BB * DD;
        const float* pqP = psq  + (size_t)(l - 1) * BB * DD;
        float* psL = psum + (size_t)l * BB * DD;
        float* pqL = psq  + (size_t)l * BB * DD;
        if (l == 0) {
            lin_mfma<false><<<(BB * NN) / 32, 256, 0, stream>>>(
                h, wgl, dinv, nullptr, nullptr, ga, gw, gb, tT);
            agg_mfma<false><<<(NN / 16) * BB, 256, 0, stream>>>(
                inst, tT, dinv, bg + l * DD, nullptr, nullptr, ga, gw, gb, h, psL, pqL);
        } else {
            lin_mfma<true><<<(BB * NN) / 32, 256, 0, stream>>>(
                h, wgl, dinv, psP, pqP, ga, gw, gb, tT);
            agg_mfma<true><<<(NN / 16) * BB, 256, 0, stream>>>(
                inst, tT, dinv, bg + l * DD, psP, pqP, ga, gw, gb, h, psL, pqL);
        }
    }
    apply_kernel<<<(BB * NN * DD / 4) / 256, 256, 0, stream>>>(
        h, psum + 2 * BB * DD, psq + 2 * BB * DD, ga, gw, gb, out);
}

// Round 11
// 289.588 us; speedup vs baseline: 1.1741x; 1.1741x over previous
//
#include <hip/hip_runtime.h>
#include <hip/hip_bf16.h>
#include <math.h>

#define BB 8
#define NN 2048
#define DD 128
#define LL 3
#define GN_EPS 1e-5f

typedef __attribute__((ext_vector_type(8))) short bf16x8;
typedef __attribute__((ext_vector_type(4))) float f32x4;
typedef __attribute__((ext_vector_type(8))) unsigned short u16x8;

// raw v_sqrt_f32 (1 inst)
#define FSQRT(x) __builtin_amdgcn_sqrtf(x)

// round-half-up f32 -> bf16 bits
__device__ __forceinline__ unsigned short f2bf(float f) {
    union { float f; unsigned u; } v; v.f = f;
    return (unsigned short)((v.u + 0x8000u) >> 16);
}

__device__ __forceinline__ float fast_tanh(float x) {
    float e = __expf(-2.0f * fabsf(x));
    float t = (1.0f - e) * __builtin_amdgcn_rcpf(1.0f + e);
    return copysignf(t, x);
}

// GraphNorm affine fold: h_norm = s*h + c
__device__ __forceinline__ void stats_sc(float ps, float pq, float a, float w_,
                                         float b_, float& s, float& c) {
    const float inv_n = 1.0f / (float)NN;
    float mean = ps * inv_n;
    float msq  = pq * inv_n;
    float var  = msq - mean * mean * a * (2.0f - a);
    float rstd = rsqrtf(var + GN_EPS);
    s = w_ * rstd;
    c = b_ - s * (a * mean);
}

// Packed layouts (16B granule = one lane's bf16x8 frag slice):
//  Ap[b][ntile(64)][kcg(64)][nt(2)][lane(64)]   value[j] = dist(n0+nt*16+ll, kcg*32+lq*8+j)
//  tp[b][kcg(64)][dt(8)][lane(64)]              value[j] = dinv*lin(h)[d=dt*16+ll][m=kcg*32+lq*8+j]

// ---------------------------------------------------------------------------
// K0: prep_wg — pack Wg (3x128x128 f32) into bf16 MFMA frag order.
// ---------------------------------------------------------------------------
__global__ __launch_bounds__(256)
void prep_wg(const float* __restrict__ Wg, unsigned short* __restrict__ wgf)
{
    const int f = blockIdx.x * 256 + threadIdx.x;    // < 3*128*128
    const int l  = f >> 14;
    const int r  = f & 16383;
    const int dp = r >> 7;
    const int e  = r & 127;
    const int dpt = dp >> 4, ll = dp & 15;
    const int kc  = e >> 5,  eo = e & 31;
    wgf[((((l * 8 + dpt) * 4 + kc) * 16 + ll) << 5) + eo] = f2bf(Wg[f]);
}

// ---------------------------------------------------------------------------
// K1: gen_pack — A (dist+I, bf16) in frag-linear packed order + dinv.
// grid 512: blockIdx = [ntile(6b)<<3 | b(3b)] (batch -> XCD).  Block owns
// rows n0..n0+31; 4 waves split K (wave w: kcg = w*16..w*16+15).
// Each lane writes sequential 16B packets; rowsums reduced for dinv.
// ---------------------------------------------------------------------------
__global__ __launch_bounds__(256)
void gen_pack(const float* __restrict__ inst, unsigned short* __restrict__ Ap,
              float* __restrict__ dinv)
{
    __shared__ float cs[NN * 2];          // 16 KB coords
    __shared__ float part[4][2][16];
    const int b     = blockIdx.x & 7;
    const int ntile = blockIdx.x >> 3;
    const int n0    = ntile * 32;
    const int tid   = threadIdx.x;
    const int w     = tid >> 6;
    const int lane  = tid & 63;
    const int lq    = lane >> 4;
    const int ll    = lane & 15;

    const float* instb = inst + b * NN * 2;
    for (int i = tid; i < (NN * 2) / 4; i += 256)
        ((float4*)cs)[i] = ((const float4*)instb)[i];
    __syncthreads();

    float nx[2], ny[2];
    #pragma unroll
    for (int nt = 0; nt < 2; ++nt) {
        int n = n0 + nt * 16 + ll;
        nx[nt] = cs[n * 2 + 0];
        ny[nt] = cs[n * 2 + 1];
    }

    // write base (16B units): (((b*64+ntile)*64 + kcg)*2 + nt)*64 + lane
    u16x8* apw = (u16x8*)Ap + (((size_t)(b * 64 + ntile) * 64 + w * 16) * 2) * 64 + lane;

    float rs[2] = { 0.f, 0.f };
    for (int kc = 0; kc < 16; ++kc) {
        const int kcg = w * 16 + kc;
        const int mb  = kcg * 32 + lq * 8;
        const float* cp = &cs[mb * 2];
        float4 c01 = *(const float4*)(cp + 0);
        float4 c23 = *(const float4*)(cp + 4);
        float4 c45 = *(const float4*)(cp + 8);
        float4 c67 = *(const float4*)(cp + 12);
        float mxx[8] = { c01.x, c01.z, c23.x, c23.z, c45.x, c45.z, c67.x, c67.z };
        float myy[8] = { c01.y, c01.w, c23.y, c23.w, c45.y, c45.w, c67.y, c67.w };
        const bool diagchunk = (kcg == ntile);
        #pragma unroll
        for (int nt = 0; nt < 2; ++nt) {
            const int n = n0 + nt * 16 + ll;
            float dist[8];
            #pragma unroll
            for (int j = 0; j < 8; ++j) {
                float dx = nx[nt] - mxx[j];
                float dy = ny[nt] - myy[j];
                dist[j] = FSQRT(dx * dx + dy * dy);
            }
            if (diagchunk) {
                #pragma unroll
                for (int j = 0; j < 8; ++j)
                    if (mb + j == n) dist[j] = 1.0f;   // self-loop
            }
            u16x8 pk;
            #pragma unroll
            for (int j = 0; j < 8; ++j) {
                pk[j] = f2bf(dist[j]);
                rs[nt] += dist[j];
            }
            apw[(size_t)kc * 128 + nt * 64] = pk;      // 2KB per kc step
        }
    }

    // rowsum reduce: lq (shfl), then cross-wave via LDS
    #pragma unroll
    for (int nt = 0; nt < 2; ++nt) {
        rs[nt] += __shfl_xor(rs[nt], 16);
        rs[nt] += __shfl_xor(rs[nt], 32);
    }
    if (lq == 0) { part[w][0][ll] = rs[0]; part[w][1][ll] = rs[1]; }
    __syncthreads();
    if (tid < 32) {
        const int nt = tid >> 4, li = tid & 15;
        float s = part[0][nt][li] + part[1][nt][li] + part[2][nt][li] + part[3][nt][li];
        dinv[b * NN + n0 + nt * 16 + li] = rsqrtf(s);  // diag already contributes 1
    }
}

// ---------------------------------------------------------------------------
// K2: proj_node + zero all per-layer stats buffers
// ---------------------------------------------------------------------------
__global__ __launch_bounds__(256)
void proj_kernel(const float* __restrict__ inst, const float* __restrict__ Wn,
                 const float* __restrict__ bn, float* __restrict__ h,
                 float* __restrict__ psum, float* __restrict__ psq)
{
    const int idx = blockIdx.x * 256 + threadIdx.x;
    const int d   = idx & (DD - 1);
    const int row = idx >> 7;
    const float x0 = inst[row * 2 + 0];
    const float x1 = inst[row * 2 + 1];
    h[idx] = x0 * Wn[d * 2 + 0] + x1 * Wn[d * 2 + 1] + bn[d];
    if (blockIdx.x == 0) {
        for (int i = threadIdx.x; i < LL * BB * DD; i += 256) {
            psum[i] = 0.0f; psq[i] = 0.0f;
        }
    }
}

// ---------------------------------------------------------------------------
// K3: lin (MFMA).  Writes tp in agg's packed frag order.
// blockIdx = [tile(6b)<<3 | b(3b)] (same swizzle as agg -> same XCD L2).
// ---------------------------------------------------------------------------
template <bool HP>
__global__ __launch_bounds__(256)
void lin_mfma(const float* __restrict__ h, const unsigned short* __restrict__ wgf_l,
              const float* __restrict__ dinv,
              const float* __restrict__ psumP, const float* __restrict__ psqP,
              const float* __restrict__ ga, const float* __restrict__ gw,
              const float* __restrict__ gb, unsigned short* __restrict__ tp)
{
    __shared__ float sL[DD], cL[DD];
    const int tid  = threadIdx.x;
    const int b    = blockIdx.x & 7;
    const int tile = blockIdx.x >> 3;
    const int row0 = b * NN + tile * 32;
    const int w    = tid >> 6;
    const int lane = tid & 63;
    const int lq   = lane >> 4;
    const int ll   = lane & 15;

    if (tid < DD) {
        float s = 1.0f, c = 0.0f;
        if (HP)
            stats_sc(psumP[b * DD + tid], psqP[b * DD + tid],
                     ga[tid], gw[tid], gb[tid], s, c);
        sL[tid] = s; cL[tid] = c;
    }
    __syncthreads();

    bf16x8 aw[2][4];
    #pragma unroll
    for (int mt = 0; mt < 2; ++mt) {
        const int dpt = 2 * w + mt;
        #pragma unroll
        for (int kc = 0; kc < 4; ++kc)
            aw[mt][kc] = *(const bf16x8*)&wgf_l[(((dpt * 4 + kc) * 16 + ll) << 5) + lq * 8];
    }

    bf16x8 bh[2][4];
    #pragma unroll
    for (int nt = 0; nt < 2; ++nt) {
        const float* hrow = h + (size_t)(row0 + nt * 16 + ll) * DD;
        #pragma unroll
        for (int kc = 0; kc < 4; ++kc) {
            float4 h0 = *(const float4*)&hrow[kc * 32 + lq * 8];
            float4 h1 = *(const float4*)&hrow[kc * 32 + lq * 8 + 4];
            const int e0 = kc * 32 + lq * 8;
            bf16x8 p;
            p[0] = (short)f2bf(fmaf(sL[e0 + 0], h0.x, cL[e0 + 0]));
            p[1] = (short)f2bf(fmaf(sL[e0 + 1], h0.y, cL[e0 + 1]));
            p[2] = (short)f2bf(fmaf(sL[e0 + 2], h0.z, cL[e0 + 2]));
            p[3] = (short)f2bf(fmaf(sL[e0 + 3], h0.w, cL[e0 + 3]));
            p[4] = (short)f2bf(fmaf(sL[e0 + 4], h1.x, cL[e0 + 4]));
            p[5] = (short)f2bf(fmaf(sL[e0 + 5], h1.y, cL[e0 + 5]));
            p[6] = (short)f2bf(fmaf(sL[e0 + 6], h1.z, cL[e0 + 6]));
            p[7] = (short)f2bf(fmaf(sL[e0 + 7], h1.w, cL[e0 + 7]));
            bh[nt][kc] = p;
        }
    }

    f32x4 acc[2][2];   // [nt][mt]
    #pragma unroll
    for (int i = 0; i < 2; ++i)
        #pragma unroll
        for (int j = 0; j < 2; ++j) acc[i][j] = (f32x4)0.0f;

    #pragma unroll
    for (int kc = 0; kc < 4; ++kc)
        #pragma unroll
        for (int nt = 0; nt < 2; ++nt)
            #pragma unroll
            for (int mt = 0; mt < 2; ++mt)
                acc[nt][mt] = __builtin_amdgcn_mfma_f32_16x16x32_bf16(
                    bh[nt][kc], aw[mt][kc], acc[nt][mt], 0, 0, 0);

    // store into packed tp: lane value (dp = (2w+mt)*16+ll, m = tile*32+nt*16+lq*4+reg)
    // idx (ushort) = (((b*64 + tile)*8 + dt)*64 + lq_a*16 + ll)*8 + j0, 4 consecutive j
    #pragma unroll
    for (int nt = 0; nt < 2; ++nt) {
        const int mloc0 = nt * 16 + lq * 4;
        const int lq_a  = mloc0 >> 3;
        const int j0    = mloc0 & 7;
        float4 di4 = *(const float4*)&dinv[row0 + mloc0];
        #pragma unroll
        for (int mt = 0; mt < 2; ++mt) {
            const int dt = 2 * w + mt;
            ushort4 pk;
            pk.x = f2bf(acc[nt][mt][0] * di4.x);
            pk.y = f2bf(acc[nt][mt][1] * di4.y);
            pk.z = f2bf(acc[nt][mt][2] * di4.z);
            pk.w = f2bf(acc[nt][mt][3] * di4.w);
            *(ushort4*)&tp[((size_t)((b * 64 + tile) * 8 + dt) * 64 + lq_a * 16 + ll) * 8 + j0] = pk;
        }
    }
}

// ---------------------------------------------------------------------------
// K4: agg — pure dual-stream packed GEMM + fused epilogue.
// Block 32n x 128d, grid 512 = [ntile<<3 | b].  4 waves split K; per chunk:
// 2 sequential A-frag loads (HBM stream) + 8 sequential tp loads (L2 stream)
// + 8 MFMAs.  2-deep register double buffer, no LDS staging, no barriers.
// ---------------------------------------------------------------------------
template <bool HP>
__global__ __launch_bounds__(256, 2)
void agg_mfma(const unsigned short* __restrict__ Ap, const unsigned short* __restrict__ tp,
              const float* __restrict__ dinv, const float* __restrict__ bg_l,
              const float* __restrict__ psumP, const float* __restrict__ psqP,
              const float* __restrict__ ga, const float* __restrict__ gw,
              const float* __restrict__ gb,
              float* __restrict__ h, float* __restrict__ psum, float* __restrict__ psq)
{
    __shared__ f32x4 red[4][8][64];       // 32 KB reduction buffer
    const int b     = blockIdx.x & 7;
    const int ntile = blockIdx.x >> 3;
    const int n0    = ntile * 32;
    const int tid   = threadIdx.x;
    const int w     = tid >> 6;
    const int lane  = tid & 63;
    const int lq    = lane >> 4;
    const int ll    = lane & 15;

    // streams (ushort units); per-kc strides: A = 1024 (2KB), tp = 4096 (8KB)
    const unsigned short* apw = Ap + (((size_t)(b * 64 + ntile) * 64 + w * 16) * 2 * 64 + lane) * 8;
    const unsigned short* tpw = tp + (((size_t)(b * 64 + w * 16) * 8) * 64 + lane) * 8;

    f32x4 acc[2][8];   // [nt][dt]
    #pragma unroll
    for (int i = 0; i < 2; ++i)
        #pragma unroll
        for (int j = 0; j < 8; ++j) acc[i][j] = (f32x4)0.0f;

    bf16x8 fa[2][2], fb[2][8];

#define LOADC(buf, kc_) { \
        const int ao = (kc_) * 1024; \
        const int to = (kc_) * 4096; \
        fa[buf][0] = *(const bf16x8*)(apw + ao); \
        fa[buf][1] = *(const bf16x8*)(apw + ao + 512); \
        _Pragma("unroll") \
        for (int dt_ = 0; dt_ < 8; ++dt_) \
            fb[buf][dt_] = *(const bf16x8*)(tpw + to + dt_ * 512); \
    }
#define DOM(buf) { \
        _Pragma("unroll") \
        for (int dt_ = 0; dt_ < 8; ++dt_) { \
            acc[0][dt_] = __builtin_amdgcn_mfma_f32_16x16x32_bf16( \
                fb[buf][dt_], fa[buf][0], acc[0][dt_], 0, 0, 0); \
            acc[1][dt_] = __builtin_amdgcn_mfma_f32_16x16x32_bf16( \
                fb[buf][dt_], fa[buf][1], acc[1][dt_], 0, 0, 0); \
        } \
    }

    LOADC(0, 0)
    #pragma unroll
    for (int kc = 0; kc < 16; ++kc) {
        if (kc < 15) LOADC((kc + 1) & 1, kc + 1)
        DOM(kc & 1)
    }
#undef LOADC
#undef DOM

    // ---- cross-wave reduction + fused epilogue (2 rounds of 8 frags)
    #pragma unroll
    for (int round = 0; round < 2; ++round) {
        #pragma unroll
        for (int nt = 0; nt < 2; ++nt)
            #pragma unroll
            for (int fd = 0; fd < 4; ++fd)
                red[w][nt * 4 + fd][lane] = acc[nt][round * 4 + fd];
        __syncthreads();

        #pragma unroll
        for (int i = 0; i < 2; ++i) {
            const int f  = w * 2 + i;
            const int nt = f >> 2;
            const int dt = round * 4 + (f & 3);
            f32x4 v = red[0][f][lane];
            v += red[1][f][lane];
            v += red[2][f][lane];
            v += red[3][f][lane];

            const int n  = n0 + nt * 16 + ll;
            const int d0 = dt * 16 + lq * 4;
            const float di = dinv[b * NN + n];
            float4 bg4 = *(const float4*)&bg_l[d0];
            float sres[4] = {1.f, 1.f, 1.f, 1.f}, cres[4] = {0.f, 0.f, 0.f, 0.f};
            if (HP) {
                float4 ps4 = *(const float4*)&psumP[b * DD + d0];
                float4 pq4 = *(const float4*)&psqP[b * DD + d0];
                float4 ga4 = *(const float4*)&ga[d0];
                float4 gw4 = *(const float4*)&gw[d0];
                float4 gb4 = *(const float4*)&gb[d0];
                stats_sc(ps4.x, pq4.x, ga4.x, gw4.x, gb4.x, sres[0], cres[0]);
                stats_sc(ps4.y, pq4.y, ga4.y, gw4.y, gb4.y, sres[1], cres[1]);
                stats_sc(ps4.z, pq4.z, ga4.z, gw4.z, gb4.z, sres[2], cres[2]);
                stats_sc(ps4.w, pq4.w, ga4.w, gw4.w, gb4.w, sres[3], cres[3]);
            }
            size_t idx = ((size_t)b * NN + n) * DD + d0;
            float4 hv = *(const float4*)&h[idx];
            float outv[4];
            #pragma unroll
            for (int r = 0; r < 4; ++r) {
                float pre = di * v[r] + (&bg4.x)[r];
                outv[r] = fast_tanh(pre) + fmaf(sres[r], (&hv.x)[r], cres[r]);
            }
            float4 ov = { outv[0], outv[1], outv[2], outv[3] };
            *(float4*)&h[idx] = ov;

            // stats: per-d sums over the 16 n's (ll dimension)
            float hs[4], hq[4];
            #pragma unroll
            for (int r = 0; r < 4; ++r) { hs[r] = outv[r]; hq[r] = outv[r] * outv[r]; }
            #pragma unroll
            for (int off = 1; off < 16; off <<= 1) {
                #pragma unroll
                for (int r = 0; r < 4; ++r) {
                    hs[r] += __shfl_xor(hs[r], off);
                    hq[r] += __shfl_xor(hq[r], off);
                }
            }
            if (ll == 0) {
                #pragma unroll
                for (int r = 0; r < 4; ++r) {
                    atomicAdd(&psum[b * DD + d0 + r], hs[r]);
                    atomicAdd(&psq[b * DD + d0 + r], hq[r]);
                }
            }
        }
        __syncthreads();
    }
}

// ---------------------------------------------------------------------------
// K5: final apply with in-thread stats from layer-2 buffers
// ---------------------------------------------------------------------------
__global__ __launch_bounds__(256)
void apply_kernel(const float* __restrict__ h,
                  const float* __restrict__ psum2, const float* __restrict__ psq2,
                  const float* __restrict__ ga, const float* __restrict__ gw,
                  const float* __restrict__ gb, float* __restrict__ dst)
{
    const int i4 = blockIdx.x * 256 + threadIdx.x;    // < B*N*D/4
    const int dg = (i4 & 31) * 4;
    const int b  = i4 >> 16;                          // N*D/4 = 65536
    float4 hv = ((const float4*)h)[i4];
    float o[4];
    #pragma unroll
    for (int j = 0; j < 4; ++j) {
        const int d = dg + j;
        float s, c;
        stats_sc(psum2[b * DD + d], psq2[b * DD + d], ga[d], gw[d], gb[d], s, c);
        o[j] = fmaf(s, (&hv.x)[j], c);
    }
    float4 ov = { o[0], o[1], o[2], o[3] };
    ((float4*)dst)[i4] = ov;
}

// ---------------------------------------------------------------------------
extern "C" void kernel_launch(void* const* d_in, const int* in_sizes, int n_in,
                              void* d_out, int out_size, void* d_ws, size_t ws_size,
                              hipStream_t stream)
{
    const float* inst = (const float*)d_in[0];
    const float* Wn   = (const float*)d_in[1];
    const float* bn   = (const float*)d_in[2];
    const float* Wg   = (const float*)d_in[3];
    const float* bg   = (const float*)d_in[4];
    const float* gw   = (const float*)d_in[5];
    const float* gb   = (const float*)d_in[6];
    const float* ga   = (const float*)d_in[7];
    float* out = (float*)d_out;

    float* ws   = (float*)d_ws;
    float* dinv = ws;                                   // B*N
    float* h    = dinv + BB * NN;                       // B*N*D
    float* psum = h + (size_t)BB * NN * DD;             // LL*B*D
    float* psq  = psum + LL * BB * DD;                  // LL*B*D
    unsigned short* wgf = (unsigned short*)(psq + LL * BB * DD);  // LL*D*D bf16
    unsigned short* tp  = wgf + LL * DD * DD;                     // B*D*N bf16 (4MB)
    unsigned short* Ap  = tp + (size_t)BB * DD * NN;              // B*N*N bf16 (64MB)

    prep_wg<<<(LL * DD * DD) / 256, 256, 0, stream>>>(Wg, wgf);
    gen_pack<<<512, 256, 0, stream>>>(inst, Ap, dinv);
    proj_kernel<<<(BB * NN * DD) / 256, 256, 0, stream>>>(inst, Wn, bn, h, psum, psq);

    for (int l = 0; l < LL; ++l) {
        const unsigned short* wgl = wgf + (size_t)l * DD * DD;
        const float* psP = psum + (size_t)(l - 1) * BB * DD;
        const float* pqP = psq  + (size_t)(l - 1) * BB * DD;
        float* psL = psum + (size_t)l * BB * DD;
        float* pqL = psq  + (size_t)l * BB * DD;
        if (l == 0) {
            lin_mfma<false><<<(BB * NN) / 32, 256, 0, stream>>>(
                h, wgl, dinv, nullptr, nullptr, ga, gw, gb, tp);
            agg_mfma<false><<<512, 256, 0, stream>>>(
                Ap, tp, dinv, bg + l * DD, nullptr, nullptr, ga, gw, gb, h, psL, pqL);
        } else {
            lin_mfma<true><<<(BB * NN) / 32, 256, 0, stream>>>(
                h, wgl, dinv, psP, pqP, ga, gw, gb, tp);
            agg_mfma<true><<<512, 256, 0, stream>>>(
                Ap, tp, dinv, bg + l * DD, psP, pqP, ga, gw, gb, h, psL, pqL);
        }
    }
    apply_kernel<<<(BB * NN * DD / 4) / 256, 256, 0, stream>>>(
        h, psum + 2 * BB * DD, psq + 2 * BB * DD, ga, gw, gb, out);
}

// Round 12
// 218.650 us; speedup vs baseline: 1.5550x; 1.3244x over previous
//
#include <hip/hip_runtime.h>
#include <hip/hip_bf16.h>
#include <math.h>

#define BB 8
#define NN 2048
#define DD 128
#define LL 3
#define GN_EPS 1e-5f

typedef __attribute__((ext_vector_type(8))) short bf16x8;
typedef __attribute__((ext_vector_type(4))) float f32x4;
typedef __attribute__((ext_vector_type(8))) unsigned short u16x8;

// raw v_sqrt_f32 (1 inst)
#define FSQRT(x) __builtin_amdgcn_sqrtf(x)

#define GLL16(gp, lp) __builtin_amdgcn_global_load_lds( \
    (const __attribute__((address_space(1))) void*)(gp), \
    (__attribute__((address_space(3))) void*)(lp), 16, 0, 0)

// s_waitcnt imm: vm_lo[3:0], exp[6:4], lgkm[11:8], vm_hi[15:14]
#define WAIT_VM1 0x0F71   // vmcnt(1), lgkm/exp nowait

// round-half-up f32 -> bf16 bits
__device__ __forceinline__ unsigned short f2bf(float f) {
    union { float f; unsigned u; } v; v.f = f;
    return (unsigned short)((v.u + 0x8000u) >> 16);
}

__device__ __forceinline__ float fast_tanh(float x) {
    float e = __expf(-2.0f * fabsf(x));
    float t = (1.0f - e) * __builtin_amdgcn_rcpf(1.0f + e);
    return copysignf(t, x);
}

// GraphNorm affine fold: h_norm = s*h + c
__device__ __forceinline__ void stats_sc(float ps, float pq, float a, float w_,
                                         float b_, float& s, float& c) {
    const float inv_n = 1.0f / (float)NN;
    float mean = ps * inv_n;
    float msq  = pq * inv_n;
    float var  = msq - mean * mean * a * (2.0f - a);
    float rstd = rsqrtf(var + GN_EPS);
    s = w_ * rstd;
    c = b_ - s * (a * mean);
}

// Packed layouts (16B granule = one lane's bf16x8 frag slice):
//  Ap[b][ntile(128)][kcg(64)][lane(64)]  value[j] = dist(ntile*16+ll, kcg*32+lq*8+j)
//  tp[b][kcg(64)][dt(8)][lane(64)]       value[j] = dinv*lin(h)[d=dt*16+ll][m=kcg*32+lq*8+j]

// ---------------------------------------------------------------------------
// K0: prep_wg — pack Wg (3x128x128 f32) into bf16 MFMA frag order.
// ---------------------------------------------------------------------------
__global__ __launch_bounds__(256)
void prep_wg(const float* __restrict__ Wg, unsigned short* __restrict__ wgf)
{
    const int f = blockIdx.x * 256 + threadIdx.x;    // < 3*128*128
    const int l  = f >> 14;
    const int r  = f & 16383;
    const int dp = r >> 7;
    const int e  = r & 127;
    const int dpt = dp >> 4, ll = dp & 15;
    const int kc  = e >> 5,  eo = e & 31;
    wgf[((((l * 8 + dpt) * 4 + kc) * 16 + ll) << 5) + eo] = f2bf(Wg[f]);
}

// ---------------------------------------------------------------------------
// K1: gen_pack — A (dist+I, bf16) in agg's frag-linear order, dinv, and
// proj_node h-init fused.  grid 1024 = [ntile(7b)<<3 | b(3b)].
// Block owns rows n0..n0+15; 4 waves K-split (wave w: kcg w*16..w*16+15).
// ---------------------------------------------------------------------------
__global__ __launch_bounds__(256)
void gen_pack(const float* __restrict__ inst, const float* __restrict__ Wn,
              const float* __restrict__ bn, unsigned short* __restrict__ Ap,
              float* __restrict__ dinv, float* __restrict__ h,
              float* __restrict__ psum, float* __restrict__ psq)
{
    __shared__ float cs[NN * 2];          // 16 KB coords
    __shared__ float part[4][16];
    const int b     = blockIdx.x & 7;
    const int ntile = blockIdx.x >> 3;    // 0..127
    const int n0    = ntile * 16;
    const int tid   = threadIdx.x;
    const int w     = tid >> 6;
    const int lane  = tid & 63;
    const int lq    = lane >> 4;
    const int ll    = lane & 15;

    const float* instb = inst + b * NN * 2;
    for (int i = tid; i < (NN * 2) / 4; i += 256)
        ((float4*)cs)[i] = ((const float4*)instb)[i];
    __syncthreads();

    const int n = n0 + ll;
    const float nx = cs[n * 2 + 0];
    const float ny = cs[n * 2 + 1];

    u16x8* apw = (u16x8*)Ap + (size_t)(b * 128 + ntile) * 64 * 64 + (w * 16) * 64 + lane;

    const int diagkcg = ntile >> 1;       // kcg whose m-range contains n0..n0+15
    float rs = 0.f;
    for (int kc = 0; kc < 16; ++kc) {
        const int kcg = w * 16 + kc;
        const int mb  = kcg * 32 + lq * 8;
        const float* cp = &cs[mb * 2];
        float4 c01 = *(const float4*)(cp + 0);
        float4 c23 = *(const float4*)(cp + 4);
        float4 c45 = *(const float4*)(cp + 8);
        float4 c67 = *(const float4*)(cp + 12);
        float mxx[8] = { c01.x, c01.z, c23.x, c23.z, c45.x, c45.z, c67.x, c67.z };
        float myy[8] = { c01.y, c01.w, c23.y, c23.w, c45.y, c45.w, c67.y, c67.w };
        float dist[8];
        #pragma unroll
        for (int j = 0; j < 8; ++j) {
            float dx = nx - mxx[j];
            float dy = ny - myy[j];
            dist[j] = FSQRT(dx * dx + dy * dy);
        }
        if (kcg == diagkcg) {
            #pragma unroll
            for (int j = 0; j < 8; ++j)
                if (mb + j == n) dist[j] = 1.0f;       // self-loop
        }
        u16x8 pk;
        #pragma unroll
        for (int j = 0; j < 8; ++j) {
            pk[j] = f2bf(dist[j]);
            rs += dist[j];
        }
        apw[kc * 64] = pk;
    }

    rs += __shfl_xor(rs, 16);
    rs += __shfl_xor(rs, 32);
    if (lq == 0) part[w][ll] = rs;
    __syncthreads();
    if (tid < 16)
        dinv[b * NN + n0 + tid] = rsqrtf(part[0][tid] + part[1][tid] +
                                         part[2][tid] + part[3][tid]);

    // fused proj: h[b][n0+r][d] = x0*Wn[d,0] + x1*Wn[d,1] + bn[d]
    {
        const int d  = tid & 127;
        const int r0 = tid >> 7;          // 0/1
        const float w0 = Wn[d * 2 + 0];
        const float w1 = Wn[d * 2 + 1];
        const float bv = bn[d];
        #pragma unroll
        for (int r = r0; r < 16; r += 2) {
            const float x0 = cs[(n0 + r) * 2 + 0];
            const float x1 = cs[(n0 + r) * 2 + 1];
            h[((size_t)b * NN + n0 + r) * DD + d] = fmaf(x0, w0, fmaf(x1, w1, bv));
        }
    }
    if (blockIdx.x == 0) {
        for (int i = tid; i < LL * BB * DD; i += 256) { psum[i] = 0.f; psq[i] = 0.f; }
    }
}

// ---------------------------------------------------------------------------
// K3: lin (MFMA).  Writes tp in agg's packed frag order.
// blockIdx = [tile(6b)<<3 | b(3b)] (batch -> XCD, same as agg).
// ---------------------------------------------------------------------------
template <bool HP>
__global__ __launch_bounds__(256)
void lin_mfma(const float* __restrict__ h, const unsigned short* __restrict__ wgf_l,
              const float* __restrict__ dinv,
              const float* __restrict__ psumP, const float* __restrict__ psqP,
              const float* __restrict__ ga, const float* __restrict__ gw,
              const float* __restrict__ gb, unsigned short* __restrict__ tp)
{
    __shared__ float sL[DD], cL[DD];
    const int tid  = threadIdx.x;
    const int b    = blockIdx.x & 7;
    const int tile = blockIdx.x >> 3;
    const int row0 = b * NN + tile * 32;
    const int w    = tid >> 6;
    const int lane = tid & 63;
    const int lq   = lane >> 4;
    const int ll   = lane & 15;

    if (tid < DD) {
        float s = 1.0f, c = 0.0f;
        if (HP)
            stats_sc(psumP[b * DD + tid], psqP[b * DD + tid],
                     ga[tid], gw[tid], gb[tid], s, c);
        sL[tid] = s; cL[tid] = c;
    }
    __syncthreads();

    bf16x8 aw[2][4];
    #pragma unroll
    for (int mt = 0; mt < 2; ++mt) {
        const int dpt = 2 * w + mt;
        #pragma unroll
        for (int kc = 0; kc < 4; ++kc)
            aw[mt][kc] = *(const bf16x8*)&wgf_l[(((dpt * 4 + kc) * 16 + ll) << 5) + lq * 8];
    }

    bf16x8 bh[2][4];
    #pragma unroll
    for (int nt = 0; nt < 2; ++nt) {
        const float* hrow = h + (size_t)(row0 + nt * 16 + ll) * DD;
        #pragma unroll
        for (int kc = 0; kc < 4; ++kc) {
            float4 h0 = *(const float4*)&hrow[kc * 32 + lq * 8];
            float4 h1 = *(const float4*)&hrow[kc * 32 + lq * 8 + 4];
            const int e0 = kc * 32 + lq * 8;
            bf16x8 p;
            p[0] = (short)f2bf(fmaf(sL[e0 + 0], h0.x, cL[e0 + 0]));
            p[1] = (short)f2bf(fmaf(sL[e0 + 1], h0.y, cL[e0 + 1]));
            p[2] = (short)f2bf(fmaf(sL[e0 + 2], h0.z, cL[e0 + 2]));
            p[3] = (short)f2bf(fmaf(sL[e0 + 3], h0.w, cL[e0 + 3]));
            p[4] = (short)f2bf(fmaf(sL[e0 + 4], h1.x, cL[e0 + 4]));
            p[5] = (short)f2bf(fmaf(sL[e0 + 5], h1.y, cL[e0 + 5]));
            p[6] = (short)f2bf(fmaf(sL[e0 + 6], h1.z, cL[e0 + 6]));
            p[7] = (short)f2bf(fmaf(sL[e0 + 7], h1.w, cL[e0 + 7]));
            bh[nt][kc] = p;
        }
    }

    f32x4 acc[2][2];   // [nt][mt]
    #pragma unroll
    for (int i = 0; i < 2; ++i)
        #pragma unroll
        for (int j = 0; j < 2; ++j) acc[i][j] = (f32x4)0.0f;

    #pragma unroll
    for (int kc = 0; kc < 4; ++kc)
        #pragma unroll
        for (int nt = 0; nt < 2; ++nt)
            #pragma unroll
            for (int mt = 0; mt < 2; ++mt)
                acc[nt][mt] = __builtin_amdgcn_mfma_f32_16x16x32_bf16(
                    bh[nt][kc], aw[mt][kc], acc[nt][mt], 0, 0, 0);

    // packed store: value (dp=(2w+mt)*16+ll, m = tile*32+nt*16+lq*4+reg)
    #pragma unroll
    for (int nt = 0; nt < 2; ++nt) {
        const int mloc0 = nt * 16 + lq * 4;            // m within the kcg=tile chunk
        const int lq_a  = mloc0 >> 3;
        const int j0    = mloc0 & 7;
        float4 di4 = *(const float4*)&dinv[row0 + mloc0];
        #pragma unroll
        for (int mt = 0; mt < 2; ++mt) {
            const int dt = 2 * w + mt;
            ushort4 pk;
            pk.x = f2bf(acc[nt][mt][0] * di4.x);
            pk.y = f2bf(acc[nt][mt][1] * di4.y);
            pk.z = f2bf(acc[nt][mt][2] * di4.z);
            pk.w = f2bf(acc[nt][mt][3] * di4.w);
            *(ushort4*)&tp[((size_t)((b * 64 + tile) * 8 + dt) * 64 + lq_a * 16 + ll) * 8 + j0] = pk;
        }
    }
}

// ---------------------------------------------------------------------------
// K4: agg — 16n x 128d tile, grid 1024 (3 blocks/CU by launch_bounds).
// Full K per block; per chunk (128 m = 4 kcg): wave stages 1 A-frag via GLL
// (3-buffer LDS, distance 2), 8 tp reg loads (2-deep dbuf), 8 MFMAs.
// Per-wave vmcnt(1) + raw s_barrier — no drain.  Waves d-split (dt {2w,2w+1})
// so the epilogue is per-wave: tanh+residual+stats, no LDS reduction.
// ---------------------------------------------------------------------------
template <bool HP>
__global__ __launch_bounds__(256, 3)
void agg_mfma(const unsigned short* __restrict__ Ap, const unsigned short* __restrict__ tp,
              const float* __restrict__ dinv, const float* __restrict__ bg_l,
              const float* __restrict__ psumP, const float* __restrict__ psqP,
              const float* __restrict__ ga, const float* __restrict__ gw,
              const float* __restrict__ gb,
              float* __restrict__ h, float* __restrict__ psum, float* __restrict__ psq)
{
    __shared__ char Abuf[3][4096];        // 12 KB: per-chunk A tile (4 frags)
    const int b     = blockIdx.x & 7;
    const int ntile = blockIdx.x >> 3;    // 0..127
    const int n0    = ntile * 16;
    const int tid   = threadIdx.x;
    const int w     = tid >> 6;
    const int lane  = tid & 63;
    const int lq    = lane >> 4;
    const int ll    = lane & 15;

    // per-lane packed sources
    const unsigned short* apsrc = Ap + ((size_t)(b * 128 + ntile) * 64) * 512 + lane * 8;
    const unsigned short* tpb   = tp + ((size_t)b * 64 * 8) * 512 + lane * 8;

    f32x4 acc[2];
    acc[0] = (f32x4)0.0f;
    acc[1] = (f32x4)0.0f;

    bf16x8 fb[2][2][4];   // [buf][dtl][s]

#define GLLA(c) GLL16(apsrc + (size_t)((((c) & 15) * 4 + w)) * 512, \
                      &Abuf[(c) % 3][w * 1024]);
#define LOADB(c) { \
        const int kb_ = ((c) & 15) * 4; \
        _Pragma("unroll") \
        for (int s_ = 0; s_ < 4; ++s_) { \
            fb[(c) & 1][0][s_] = *(const bf16x8*)(tpb + (size_t)((kb_ + s_) * 8 + 2 * w + 0) * 512); \
            fb[(c) & 1][1][s_] = *(const bf16x8*)(tpb + (size_t)((kb_ + s_) * 8 + 2 * w + 1) * 512); \
        } \
    }

    // prologue: A(0), B(0), A(1)  -> per-wave pending [A0(1), B0(8), A1(1)]
    GLLA(0)
    LOADB(0)
    GLLA(1)

    #pragma unroll 4
    for (int k = 0; k < 16; ++k) {
        __builtin_amdgcn_s_waitcnt(WAIT_VM1);   // A(k)+B(k) landed; A(k+1) in flight
        __builtin_amdgcn_s_barrier();           // all waves' A(k) in LDS
        __builtin_amdgcn_sched_barrier(0);
        bf16x8 af[4];
        const char* lb = &Abuf[k % 3][0];
        #pragma unroll
        for (int s = 0; s < 4; ++s)
            af[s] = *(const bf16x8*)(lb + s * 1024 + lane * 16);
        LOADB(k + 1)                            // B first, then A: keeps vmcnt(1) exact
        GLLA(k + 2)
        #pragma unroll
        for (int s = 0; s < 4; ++s) {
            acc[0] = __builtin_amdgcn_mfma_f32_16x16x32_bf16(fb[k & 1][0][s], af[s], acc[0], 0, 0, 0);
            acc[1] = __builtin_amdgcn_mfma_f32_16x16x32_bf16(fb[k & 1][1][s], af[s], acc[1], 0, 0, 0);
        }
    }
#undef GLLA
#undef LOADB

    // ---- per-wave epilogue: lane holds n = n0+ll, d = (2w+dtl)*16+lq*4+reg
    const int n  = n0 + ll;
    const float di = dinv[b * NN + n];
    #pragma unroll
    for (int dtl = 0; dtl < 2; ++dtl) {
        const int d0 = (2 * w + dtl) * 16 + lq * 4;
        float4 bg4 = *(const float4*)&bg_l[d0];
        float sres[4] = {1.f, 1.f, 1.f, 1.f}, cres[4] = {0.f, 0.f, 0.f, 0.f};
        if (HP) {
            float4 ps4 = *(const float4*)&psumP[b * DD + d0];
            float4 pq4 = *(const float4*)&psqP[b * DD + d0];
            float4 ga4 = *(const float4*)&ga[d0];
            float4 gw4 = *(const float4*)&gw[d0];
            float4 gb4 = *(const float4*)&gb[d0];
            stats_sc(ps4.x, pq4.x, ga4.x, gw4.x, gb4.x, sres[0], cres[0]);
            stats_sc(ps4.y, pq4.y, ga4.y, gw4.y, gb4.y, sres[1], cres[1]);
            stats_sc(ps4.z, pq4.z, ga4.z, gw4.z, gb4.z, sres[2], cres[2]);
            stats_sc(ps4.w, pq4.w, ga4.w, gw4.w, gb4.w, sres[3], cres[3]);
        }
        size_t idx = ((size_t)b * NN + n) * DD + d0;
        float4 hv = *(const float4*)&h[idx];
        float outv[4];
        #pragma unroll
        for (int r = 0; r < 4; ++r) {
            float pre = di * acc[dtl][r] + (&bg4.x)[r];
            outv[r] = fast_tanh(pre) + fmaf(sres[r], (&hv.x)[r], cres[r]);
        }
        float4 ov = { outv[0], outv[1], outv[2], outv[3] };
        *(float4*)&h[idx] = ov;

        // stats: reduce over the 16 n's (ll lanes)
        float hs[4], hq[4];
        #pragma unroll
        for (int r = 0; r < 4; ++r) { hs[r] = outv[r]; hq[r] = outv[r] * outv[r]; }
        #pragma unroll
        for (int off = 1; off < 16; off <<= 1) {
            #pragma unroll
            for (int r = 0; r < 4; ++r) {
                hs[r] += __shfl_xor(hs[r], off);
                hq[r] += __shfl_xor(hq[r], off);
            }
        }
        if (ll == 0) {
            #pragma unroll
            for (int r = 0; r < 4; ++r) {
                atomicAdd(&psum[b * DD + d0 + r], hs[r]);
                atomicAdd(&psq[b * DD + d0 + r], hq[r]);
            }
        }
    }
}

// ---------------------------------------------------------------------------
// K5: final apply with in-thread stats from layer-2 buffers
// ---------------------------------------------------------------------------
__global__ __launch_bounds__(256)
void apply_kernel(const float* __restrict__ h,
                  const float* __restrict__ psum2, const float* __restrict__ psq2,
                  const float* __restrict__ ga, const float* __restrict__ gw,
                  const float* __restrict__ gb, float* __restrict__ dst)
{
    const int i4 = blockIdx.x * 256 + threadIdx.x;    // < B*N*D/4
    const int dg = (i4 & 31) * 4;
    const int b  = i4 >> 16;                          // N*D/4 = 65536
    float4 hv = ((const float4*)h)[i4];
    float o[4];
    #pragma unroll
    for (int j = 0; j < 4; ++j) {
        const int d = dg + j;
        float s, c;
        stats_sc(psum2[b * DD + d], psq2[b * DD + d], ga[d], gw[d], gb[d], s, c);
        o[j] = fmaf(s, (&hv.x)[j], c);
    }
    float4 ov = { o[0], o[1], o[2], o[3] };
    ((float4*)dst)[i4] = ov;
}

// ---------------------------------------------------------------------------
extern "C" void kernel_launch(void* const* d_in, const int* in_sizes, int n_in,
                              void* d_out, int out_size, void* d_ws, size_t ws_size,
                              hipStream_t stream)
{
    const float* inst = (const float*)d_in[0];
    const float* Wn   = (const float*)d_in[1];
    const float* bn   = (const float*)d_in[2];
    const float* Wg   = (const float*)d_in[3];
    const float* bg   = (const float*)d_in[4];
    const float* gw   = (const float*)d_in[5];
    const float* gb   = (const float*)d_in[6];
    const float* ga   = (const float*)d_in[7];
    float* out = (float*)d_out;

    float* ws   = (float*)d_ws;
    float* dinv = ws;                                   // B*N
    float* h    = dinv + BB * NN;                       // B*N*D
    float* psum = h + (size_t)BB * NN * DD;             // LL*B*D
    float* psq  = psum + LL * BB * DD;                  // LL*B*D
    unsigned short* wgf = (unsigned short*)(psq + LL * BB * DD);  // LL*D*D bf16
    unsigned short* tp  = wgf + LL * DD * DD;                     // B*D*N bf16 (4MB)
    unsigned short* Ap  = tp + (size_t)BB * DD * NN;              // B*N*N bf16 (64MB)

    prep_wg<<<(LL * DD * DD) / 256, 256, 0, stream>>>(Wg, wgf);
    gen_pack<<<1024, 256, 0, stream>>>(inst, Wn, bn, Ap, dinv, h, psum, psq);

    for (int l = 0; l < LL; ++l) {
        const unsigned short* wgl = wgf + (size_t)l * DD * DD;
        const float* psP = psum + (size_t)(l - 1) * BB * DD;
        const float* pqP = psq  + (size_t)(l - 1) * BB * DD;
        float* psL = psum + (size_t)l * BB * DD;
        float* pqL = psq  + (size_t)l * BB * DD;
        if (l == 0) {
            lin_mfma<false><<<(BB * NN) / 32, 256, 0, stream>>>(
                h, wgl, dinv, nullptr, nullptr, ga, gw, gb, tp);
            agg_mfma<false><<<1024, 256, 0, stream>>>(
                Ap, tp, dinv, bg + l * DD, nullptr, nullptr, ga, gw, gb, h, psL, pqL);
        } else {
            lin_mfma<true><<<(BB * NN) / 32, 256, 0, stream>>>(
                h, wgl, dinv, psP, pqP, ga, gw, gb, tp);
            agg_mfma<true><<<1024, 256, 0, stream>>>(
                Ap, tp, dinv, bg + l * DD, psP, pqP, ga, gw, gb, h, psL, pqL);
        }
    }
    apply_kernel<<<(BB * NN * DD / 4) / 256, 256, 0, stream>>>(
        h, psum + 2 * BB * DD, psq + 2 * BB * DD, ga, gw, gb, out);
}

// Round 13
// 216.036 us; speedup vs baseline: 1.5739x; 1.0121x over previous
//
#include <hip/hip_runtime.h>
#include <hip/hip_bf16.h>
#include <math.h>

#define BB 8
#define NN 2048
#define DD 128
#define LL 3
#define GN_EPS 1e-5f

typedef __attribute__((ext_vector_type(8))) short bf16x8;
typedef __attribute__((ext_vector_type(4))) float f32x4;
typedef __attribute__((ext_vector_type(8))) unsigned short u16x8;

// raw v_sqrt_f32 (1 inst)
#define FSQRT(x) __builtin_amdgcn_sqrtf(x)

#define GLL16(gp, lp) __builtin_amdgcn_global_load_lds( \
    (const __attribute__((address_space(1))) void*)(gp), \
    (__attribute__((address_space(3))) void*)(lp), 16, 0, 0)

// s_waitcnt imm: vm_lo[3:0], exp[6:4], lgkm[11:8], vm_hi[15:14]
#define WAIT_VM10 0x0F7A   // vmcnt(10), lgkm/exp nowait

// round-half-up f32 -> bf16 bits
__device__ __forceinline__ unsigned short f2bf(float f) {
    union { float f; unsigned u; } v; v.f = f;
    return (unsigned short)((v.u + 0x8000u) >> 16);
}

__device__ __forceinline__ float fast_tanh(float x) {
    float e = __expf(-2.0f * fabsf(x));
    float t = (1.0f - e) * __builtin_amdgcn_rcpf(1.0f + e);
    return copysignf(t, x);
}

// GraphNorm affine fold: h_norm = s*h + c
__device__ __forceinline__ void stats_sc(float ps, float pq, float a, float w_,
                                         float b_, float& s, float& c) {
    const float inv_n = 1.0f / (float)NN;
    float mean = ps * inv_n;
    float msq  = pq * inv_n;
    float var  = msq - mean * mean * a * (2.0f - a);
    float rstd = rsqrtf(var + GN_EPS);
    s = w_ * rstd;
    c = b_ - s * (a * mean);
}

// Packed layouts (16B granule = one lane's bf16x8 frag slice):
//  Ap[b][ntile(128)][kcg(64)][lane(64)]  value[j] = dist(ntile*16+ll, kcg*32+lq*8+j)
//  tp[b][kcg(64)][dt(8)][lane(64)]       value[j] = dinv*lin(h)[d=dt*16+ll][m=kcg*32+lq*8+j]

// ---------------------------------------------------------------------------
// K0: prep_wg — pack Wg (3x128x128 f32) into bf16 MFMA frag order.
// ---------------------------------------------------------------------------
__global__ __launch_bounds__(256)
void prep_wg(const float* __restrict__ Wg, unsigned short* __restrict__ wgf)
{
    const int f = blockIdx.x * 256 + threadIdx.x;    // < 3*128*128
    const int l  = f >> 14;
    const int r  = f & 16383;
    const int dp = r >> 7;
    const int e  = r & 127;
    const int dpt = dp >> 4, ll = dp & 15;
    const int kc  = e >> 5,  eo = e & 31;
    wgf[((((l * 8 + dpt) * 4 + kc) * 16 + ll) << 5) + eo] = f2bf(Wg[f]);
}

// ---------------------------------------------------------------------------
// K1: gen_pack — A (dist+I, bf16) in agg's frag-linear order, dinv, and
// proj_node h-init fused.  grid 1024 = [ntile(7b)<<3 | b(3b)].
// ---------------------------------------------------------------------------
__global__ __launch_bounds__(256)
void gen_pack(const float* __restrict__ inst, const float* __restrict__ Wn,
              const float* __restrict__ bn, unsigned short* __restrict__ Ap,
              float* __restrict__ dinv, float* __restrict__ h,
              float* __restrict__ psum, float* __restrict__ psq)
{
    __shared__ float cs[NN * 2];          // 16 KB coords
    __shared__ float part[4][16];
    const int b     = blockIdx.x & 7;
    const int ntile = blockIdx.x >> 3;    // 0..127
    const int n0    = ntile * 16;
    const int tid   = threadIdx.x;
    const int w     = tid >> 6;
    const int lane  = tid & 63;
    const int lq    = lane >> 4;
    const int ll    = lane & 15;

    const float* instb = inst + b * NN * 2;
    for (int i = tid; i < (NN * 2) / 4; i += 256)
        ((float4*)cs)[i] = ((const float4*)instb)[i];
    __syncthreads();

    const int n = n0 + ll;
    const float nx = cs[n * 2 + 0];
    const float ny = cs[n * 2 + 1];

    u16x8* apw = (u16x8*)Ap + (size_t)(b * 128 + ntile) * 64 * 64 + (w * 16) * 64 + lane;

    const int diagkcg = ntile >> 1;       // kcg whose m-range contains n0..n0+15
    float rs = 0.f;
    for (int kc = 0; kc < 16; ++kc) {
        const int kcg = w * 16 + kc;
        const int mb  = kcg * 32 + lq * 8;
        const float* cp = &cs[mb * 2];
        float4 c01 = *(const float4*)(cp + 0);
        float4 c23 = *(const float4*)(cp + 4);
        float4 c45 = *(const float4*)(cp + 8);
        float4 c67 = *(const float4*)(cp + 12);
        float mxx[8] = { c01.x, c01.z, c23.x, c23.z, c45.x, c45.z, c67.x, c67.z };
        float myy[8] = { c01.y, c01.w, c23.y, c23.w, c45.y, c45.w, c67.y, c67.w };
        float dist[8];
        #pragma unroll
        for (int j = 0; j < 8; ++j) {
            float dx = nx - mxx[j];
            float dy = ny - myy[j];
            dist[j] = FSQRT(dx * dx + dy * dy);
        }
        if (kcg == diagkcg) {
            #pragma unroll
            for (int j = 0; j < 8; ++j)
                if (mb + j == n) dist[j] = 1.0f;       // self-loop
        }
        u16x8 pk;
        #pragma unroll
        for (int j = 0; j < 8; ++j) {
            pk[j] = f2bf(dist[j]);
            rs += dist[j];
        }
        apw[kc * 64] = pk;
    }

    rs += __shfl_xor(rs, 16);
    rs += __shfl_xor(rs, 32);
    if (lq == 0) part[w][ll] = rs;
    __syncthreads();
    if (tid < 16)
        dinv[b * NN + n0 + tid] = rsqrtf(part[0][tid] + part[1][tid] +
                                         part[2][tid] + part[3][tid]);

    // fused proj: h[b][n0+r][d] = x0*Wn[d,0] + x1*Wn[d,1] + bn[d]
    {
        const int d  = tid & 127;
        const int r0 = tid >> 7;          // 0/1
        const float w0 = Wn[d * 2 + 0];
        const float w1 = Wn[d * 2 + 1];
        const float bv = bn[d];
        #pragma unroll
        for (int r = r0; r < 16; r += 2) {
            const float x0 = cs[(n0 + r) * 2 + 0];
            const float x1 = cs[(n0 + r) * 2 + 1];
            h[((size_t)b * NN + n0 + r) * DD + d] = fmaf(x0, w0, fmaf(x1, w1, bv));
        }
    }
    if (blockIdx.x == 0) {
        for (int i = tid; i < LL * BB * DD; i += 256) { psum[i] = 0.f; psq[i] = 0.f; }
    }
}

// ---------------------------------------------------------------------------
// K3: lin (MFMA).  Writes tp in agg's packed frag order.
// blockIdx = [tile(6b)<<3 | b(3b)] (batch -> XCD, same as agg).
// ---------------------------------------------------------------------------
template <bool HP>
__global__ __launch_bounds__(256)
void lin_mfma(const float* __restrict__ h, const unsigned short* __restrict__ wgf_l,
              const float* __restrict__ dinv,
              const float* __restrict__ psumP, const float* __restrict__ psqP,
              const float* __restrict__ ga, const float* __restrict__ gw,
              const float* __restrict__ gb, unsigned short* __restrict__ tp)
{
    __shared__ float sL[DD], cL[DD];
    const int tid  = threadIdx.x;
    const int b    = blockIdx.x & 7;
    const int tile = blockIdx.x >> 3;
    const int row0 = b * NN + tile * 32;
    const int w    = tid >> 6;
    const int lane = tid & 63;
    const int lq   = lane >> 4;
    const int ll   = lane & 15;

    if (tid < DD) {
        float s = 1.0f, c = 0.0f;
        if (HP)
            stats_sc(psumP[b * DD + tid], psqP[b * DD + tid],
                     ga[tid], gw[tid], gb[tid], s, c);
        sL[tid] = s; cL[tid] = c;
    }
    __syncthreads();

    bf16x8 aw[2][4];
    #pragma unroll
    for (int mt = 0; mt < 2; ++mt) {
        const int dpt = 2 * w + mt;
        #pragma unroll
        for (int kc = 0; kc < 4; ++kc)
            aw[mt][kc] = *(const bf16x8*)&wgf_l[(((dpt * 4 + kc) * 16 + ll) << 5) + lq * 8];
    }

    bf16x8 bh[2][4];
    #pragma unroll
    for (int nt = 0; nt < 2; ++nt) {
        const float* hrow = h + (size_t)(row0 + nt * 16 + ll) * DD;
        #pragma unroll
        for (int kc = 0; kc < 4; ++kc) {
            float4 h0 = *(const float4*)&hrow[kc * 32 + lq * 8];
            float4 h1 = *(const float4*)&hrow[kc * 32 + lq * 8 + 4];
            const int e0 = kc * 32 + lq * 8;
            bf16x8 p;
            p[0] = (short)f2bf(fmaf(sL[e0 + 0], h0.x, cL[e0 + 0]));
            p[1] = (short)f2bf(fmaf(sL[e0 + 1], h0.y, cL[e0 + 1]));
            p[2] = (short)f2bf(fmaf(sL[e0 + 2], h0.z, cL[e0 + 2]));
            p[3] = (short)f2bf(fmaf(sL[e0 + 3], h0.w, cL[e0 + 3]));
            p[4] = (short)f2bf(fmaf(sL[e0 + 4], h1.x, cL[e0 + 4]));
            p[5] = (short)f2bf(fmaf(sL[e0 + 5], h1.y, cL[e0 + 5]));
            p[6] = (short)f2bf(fmaf(sL[e0 + 6], h1.z, cL[e0 + 6]));
            p[7] = (short)f2bf(fmaf(sL[e0 + 7], h1.w, cL[e0 + 7]));
            bh[nt][kc] = p;
        }
    }

    f32x4 acc[2][2];   // [nt][mt]
    #pragma unroll
    for (int i = 0; i < 2; ++i)
        #pragma unroll
        for (int j = 0; j < 2; ++j) acc[i][j] = (f32x4)0.0f;

    #pragma unroll
    for (int kc = 0; kc < 4; ++kc)
        #pragma unroll
        for (int nt = 0; nt < 2; ++nt)
            #pragma unroll
            for (int mt = 0; mt < 2; ++mt)
                acc[nt][mt] = __builtin_amdgcn_mfma_f32_16x16x32_bf16(
                    bh[nt][kc], aw[mt][kc], acc[nt][mt], 0, 0, 0);

    // packed store: value (dp=(2w+mt)*16+ll, m = tile*32+nt*16+lq*4+reg)
    #pragma unroll
    for (int nt = 0; nt < 2; ++nt) {
        const int mloc0 = nt * 16 + lq * 4;            // m within the kcg=tile chunk
        const int lq_a  = mloc0 >> 3;
        const int j0    = mloc0 & 7;
        float4 di4 = *(const float4*)&dinv[row0 + mloc0];
        #pragma unroll
        for (int mt = 0; mt < 2; ++mt) {
            const int dt = 2 * w + mt;
            ushort4 pk;
            pk.x = f2bf(acc[nt][mt][0] * di4.x);
            pk.y = f2bf(acc[nt][mt][1] * di4.y);
            pk.z = f2bf(acc[nt][mt][2] * di4.z);
            pk.w = f2bf(acc[nt][mt][3] * di4.w);
            *(ushort4*)&tp[((size_t)((b * 64 + tile) * 8 + dt) * 64 + lq_a * 16 + ll) * 8 + j0] = pk;
        }
    }
}

// ---------------------------------------------------------------------------
// K4: agg — 16n x 128d tile, grid 1024, 3 blocks/CU.
// Deep pipeline matched to measured latencies: A (HBM stream) via GLL at
// distance 6 (7-buffer LDS ring, 28 KB), B (tp, L2) at distance 2 (3 reg
// buffers).  Steady queue at iter top = [A(k+1..3), B(k)x8, A(k+4), B(k+1)x8,
// A(k+5)] -> vmcnt(10) drains exactly A(k)+B(k).  Raw s_barrier (no drain).
// Waves d-split (dt {2w,2w+1}), full K each — per-wave epilogue, no reduction.
// ---------------------------------------------------------------------------
template <bool HP>
__global__ __launch_bounds__(256, 3)
void agg_mfma(const unsigned short* __restrict__ Ap, const unsigned short* __restrict__ tp,
              const float* __restrict__ dinv, const float* __restrict__ bg_l,
              const float* __restrict__ psumP, const float* __restrict__ psqP,
              const float* __restrict__ ga, const float* __restrict__ gw,
              const float* __restrict__ gb,
              float* __restrict__ h, float* __restrict__ psum, float* __restrict__ psq)
{
    __shared__ char Abuf[7][4096];        // 28 KB: ring of 7 chunk-tiles (4 frags each)
    const int b     = blockIdx.x & 7;
    const int ntile = blockIdx.x >> 3;    // 0..127
    const int n0    = ntile * 16;
    const int tid   = threadIdx.x;
    const int w     = tid >> 6;
    const int lane  = tid & 63;
    const int lq    = lane >> 4;
    const int ll    = lane & 15;

    // per-lane packed sources
    const unsigned short* apsrc = Ap + ((size_t)(b * 128 + ntile) * 64) * 512 + lane * 8;
    const unsigned short* tpb   = tp + ((size_t)b * 64 * 8) * 512 + lane * 8;

    f32x4 acc[2];
    acc[0] = (f32x4)0.0f;
    acc[1] = (f32x4)0.0f;

    bf16x8 fb[3][2][4];   // [ringbuf][dtl][s]

#define GLLA(c) GLL16(apsrc + (size_t)((((c) & 15) * 4 + w)) * 512, \
                      &Abuf[(c) % 7][w * 1024]);
#define LOADB(c) { \
        const int kb_ = ((c) & 15) * 4; \
        _Pragma("unroll") \
        for (int s_ = 0; s_ < 4; ++s_) { \
            fb[(c) % 3][0][s_] = *(const bf16x8*)(tpb + (size_t)((kb_ + s_) * 8 + 2 * w + 0) * 512); \
            fb[(c) % 3][1][s_] = *(const bf16x8*)(tpb + (size_t)((kb_ + s_) * 8 + 2 * w + 1) * 512); \
        } \
    }

    // prologue — issue order defines the vm queue; B(0) AFTER A(0..3) so that
    // draining B(0) at iter 0 only force-drains A(1..3) (already ~landed).
    GLLA(0) GLLA(1) GLLA(2) GLLA(3)
    LOADB(0)
    GLLA(4)
    LOADB(1)
    GLLA(5)

    #pragma unroll
    for (int k = 0; k < 16; ++k) {
        __builtin_amdgcn_s_waitcnt(WAIT_VM10);  // A(k)+B(k) landed; rest in flight
        __builtin_amdgcn_s_barrier();           // all waves' A(k) in LDS
        __builtin_amdgcn_sched_barrier(0);
        bf16x8 af[4];
        const char* lb = &Abuf[k % 7][0];
        #pragma unroll
        for (int s = 0; s < 4; ++s)
            af[s] = *(const bf16x8*)(lb + s * 1024 + lane * 16);
        LOADB(k + 2)                            // B first, then A: queue order fixed
        GLLA(k + 6)
        __builtin_amdgcn_sched_barrier(0);
        #pragma unroll
        for (int s = 0; s < 4; ++s) {
            acc[0] = __builtin_amdgcn_mfma_f32_16x16x32_bf16(fb[k % 3][0][s], af[s], acc[0], 0, 0, 0);
            acc[1] = __builtin_amdgcn_mfma_f32_16x16x32_bf16(fb[k % 3][1][s], af[s], acc[1], 0, 0, 0);
        }
    }
#undef GLLA
#undef LOADB

    // ---- per-wave epilogue: lane holds n = n0+ll, d = (2w+dtl)*16+lq*4+reg
    const int n  = n0 + ll;
    const float di = dinv[b * NN + n];
    #pragma unroll
    for (int dtl = 0; dtl < 2; ++dtl) {
        const int d0 = (2 * w + dtl) * 16 + lq * 4;
        float4 bg4 = *(const float4*)&bg_l[d0];
        float sres[4] = {1.f, 1.f, 1.f, 1.f}, cres[4] = {0.f, 0.f, 0.f, 0.f};
        if (HP) {
            float4 ps4 = *(const float4*)&psumP[b * DD + d0];
            float4 pq4 = *(const float4*)&psqP[b * DD + d0];
            float4 ga4 = *(const float4*)&ga[d0];
            float4 gw4 = *(const float4*)&gw[d0];
            float4 gb4 = *(const float4*)&gb[d0];
            stats_sc(ps4.x, pq4.x, ga4.x, gw4.x, gb4.x, sres[0], cres[0]);
            stats_sc(ps4.y, pq4.y, ga4.y, gw4.y, gb4.y, sres[1], cres[1]);
            stats_sc(ps4.z, pq4.z, ga4.z, gw4.z, gb4.z, sres[2], cres[2]);
            stats_sc(ps4.w, pq4.w, ga4.w, gw4.w, gb4.w, sres[3], cres[3]);
        }
        size_t idx = ((size_t)b * NN + n) * DD + d0;
        float4 hv = *(const float4*)&h[idx];
        float outv[4];
        #pragma unroll
        for (int r = 0; r < 4; ++r) {
            float pre = di * acc[dtl][r] + (&bg4.x)[r];
            outv[r] = fast_tanh(pre) + fmaf(sres[r], (&hv.x)[r], cres[r]);
        }
        float4 ov = { outv[0], outv[1], outv[2], outv[3] };
        *(float4*)&h[idx] = ov;

        // stats: reduce over the 16 n's (ll lanes)
        float hs[4], hq[4];
        #pragma unroll
        for (int r = 0; r < 4; ++r) { hs[r] = outv[r]; hq[r] = outv[r] * outv[r]; }
        #pragma unroll
        for (int off = 1; off < 16; off <<= 1) {
            #pragma unroll
            for (int r = 0; r < 4; ++r) {
                hs[r] += __shfl_xor(hs[r], off);
                hq[r] += __shfl_xor(hq[r], off);
            }
        }
        if (ll == 0) {
            #pragma unroll
            for (int r = 0; r < 4; ++r) {
                atomicAdd(&psum[b * DD + d0 + r], hs[r]);
                atomicAdd(&psq[b * DD + d0 + r], hq[r]);
            }
        }
    }
}

// ---------------------------------------------------------------------------
// K5: final apply with in-thread stats from layer-2 buffers
// ---------------------------------------------------------------------------
__global__ __launch_bounds__(256)
void apply_kernel(const float* __restrict__ h,
                  const float* __restrict__ psum2, const float* __restrict__ psq2,
                  const float* __restrict__ ga, const float* __restrict__ gw,
                  const float* __restrict__ gb, float* __restrict__ dst)
{
    const int i4 = blockIdx.x * 256 + threadIdx.x;    // < B*N*D/4
    const int dg = (i4 & 31) * 4;
    const int b  = i4 >> 16;                          // N*D/4 = 65536
    float4 hv = ((const float4*)h)[i4];
    float o[4];
    #pragma unroll
    for (int j = 0; j < 4; ++j) {
        const int d = dg + j;
        float s, c;
        stats_sc(psum2[b * DD + d], psq2[b * DD + d], ga[d], gw[d], gb[d], s, c);
        o[j] = fmaf(s, (&hv.x)[j], c);
    }
    float4 ov = { o[0], o[1], o[2], o[3] };
    ((float4*)dst)[i4] = ov;
}

// ---------------------------------------------------------------------------
extern "C" void kernel_launch(void* const* d_in, const int* in_sizes, int n_in,
                              void* d_out, int out_size, void* d_ws, size_t ws_size,
                              hipStream_t stream)
{
    const float* inst = (const float*)d_in[0];
    const float* Wn   = (const float*)d_in[1];
    const float* bn   = (const float*)d_in[2];
    const float* Wg   = (const float*)d_in[3];
    const float* bg   = (const float*)d_in[4];
    const float* gw   = (const float*)d_in[5];
    const float* gb   = (const float*)d_in[6];
    const float* ga   = (const float*)d_in[7];
    float* out = (float*)d_out;

    float* ws   = (float*)d_ws;
    float* dinv = ws;                                   // B*N
    float* h    = dinv + BB * NN;                       // B*N*D
    float* psum = h + (size_t)BB * NN * DD;             // LL*B*D
    float* psq  = psum + LL * BB * DD;                  // LL*B*D
    unsigned short* wgf = (unsigned short*)(psq + LL * BB * DD);  // LL*D*D bf16
    unsigned short* tp  = wgf + LL * DD * DD;                     // B*D*N bf16 (4MB)
    unsigned short* Ap  = tp + (size_t)BB * DD * NN;              // B*N*N bf16 (64MB)

    prep_wg<<<(LL * DD * DD) / 256, 256, 0, stream>>>(Wg, wgf);
    gen_pack<<<1024, 256, 0, stream>>>(inst, Wn, bn, Ap, dinv, h, psum, psq);

    for (int l = 0; l < LL; ++l) {
        const unsigned short* wgl = wgf + (size_t)l * DD * DD;
        const float* psP = psum + (size_t)(l - 1) * BB * DD;
        const float* pqP = psq  + (size_t)(l - 1) * BB * DD;
        float* psL = psum + (size_t)l * BB * DD;
        float* pqL = psq  + (size_t)l * BB * DD;
        if (l == 0) {
            lin_mfma<false><<<(BB * NN) / 32, 256, 0, stream>>>(
                h, wgl, dinv, nullptr, nullptr, ga, gw, gb, tp);
            agg_mfma<false><<<1024, 256, 0, stream>>>(
                Ap, tp, dinv, bg + l * DD, nullptr, nullptr, ga, gw, gb, h, psL, pqL);
        } else {
            lin_mfma<true><<<(BB * NN) / 32, 256, 0, stream>>>(
                h, wgl, dinv, psP, pqP, ga, gw, gb, tp);
            agg_mfma<true><<<1024, 256, 0, stream>>>(
                Ap, tp, dinv, bg + l * DD, psP, pqP, ga, gw, gb, h, psL, pqL);
        }
    }
    apply_kernel<<<(BB * NN * DD / 4) / 256, 256, 0, stream>>>(
        h, psum + 2 * BB * DD, psq + 2 * BB * DD, ga, gw, gb, out);
}